// Round 4
// baseline (663.992 us; speedup 1.0000x reference)
//
#include <hip/hip_runtime.h>
#include <hip/hip_bf16.h>
#include <math.h>

#define NN 50000
#define NE 800000
#define COUT 32
#define KK 10
#define HXW 352            // K*OUT + OUT  (h columns 0..319, root columns 320..351)
#define EPSV 1e-15f
#define SCAN_NB 196        // ceil(50000/256)

// ================= CSR build (once per call) =================

__global__ void count_deg(const int* __restrict__ ei, int* __restrict__ srcdeg,
                          int* __restrict__ dstdeg) {
    int e = blockIdx.x * 256 + threadIdx.x;
    if (e >= NE) return;
    atomicAdd(srcdeg + ei[e], 1);
    atomicAdd(dstdeg + ei[NE + e], 1);
}

__device__ __forceinline__ int block_incl_scan(int v, int* s) {
    int t = threadIdx.x;
    s[t] = v; __syncthreads();
#pragma unroll
    for (int off = 1; off < 256; off <<= 1) {
        int u = (t >= off) ? s[t - off] : 0;
        __syncthreads();
        s[t] += u; __syncthreads();
    }
    int r = s[t]; __syncthreads();
    return r;
}

// per-256-chunk sums of srcdeg/dstdeg
__global__ __launch_bounds__(256) void scan_partial(const int* __restrict__ srcdeg,
                                                    const int* __restrict__ dstdeg,
                                                    int* __restrict__ bsumS,
                                                    int* __restrict__ bsumD) {
    __shared__ int s[256];
    int i = blockIdx.x * 256 + threadIdx.x;
    int vs = (i < NN) ? srcdeg[i] : 0;
    int vd = (i < NN) ? dstdeg[i] : 0;
    int is = block_incl_scan(vs, s);
    int id = block_incl_scan(vd, s);
    if (threadIdx.x == 255) { bsumS[blockIdx.x] = is; bsumD[blockIdx.x] = id; }
}

// single small block: exclusive scan of the 196 partials
__global__ __launch_bounds__(256) void scan_blocks(int* __restrict__ bsumS,
                                                   int* __restrict__ bsumD,
                                                   int* __restrict__ bposS,
                                                   int* __restrict__ bposD) {
    __shared__ int s[256];
    int t = threadIdx.x;
    int vs = (t < SCAN_NB) ? bsumS[t] : 0;
    int vd = (t < SCAN_NB) ? bsumD[t] : 0;
    int is = block_incl_scan(vs, s);
    int id = block_incl_scan(vd, s);
    if (t < SCAN_NB) { bposS[t] = is - vs; bposD[t] = id - vd; }
}

// final: rowptr/cursor for both CSRs + invdeg
__global__ __launch_bounds__(256) void scan_final(const int* __restrict__ srcdeg,
                                                  const int* __restrict__ dstdeg,
                                                  const int* __restrict__ bposS,
                                                  const int* __restrict__ bposD,
                                                  int* __restrict__ rpS, int* __restrict__ curS,
                                                  int* __restrict__ rpD, int* __restrict__ curD,
                                                  float* __restrict__ invdeg) {
    __shared__ int s[256];
    int i = blockIdx.x * 256 + threadIdx.x;
    int vs = (i < NN) ? srcdeg[i] : 0;
    int vd = (i < NN) ? dstdeg[i] : 0;
    int is = block_incl_scan(vs, s);
    int id = block_incl_scan(vd, s);
    if (i < NN) {
        int es = bposS[blockIdx.x] + is - vs;
        int ed = bposD[blockIdx.x] + id - vd;
        rpS[i] = es; curS[i] = es;
        rpD[i] = ed; curD[i] = ed;
        invdeg[i] = 1.0f / fmaxf((float)vd, 1.0f);
    }
    if (i == NN) { rpS[NN] = NE; rpD[NN] = NE; }
}

// assign slots: src-slot gets (dst-slot, edge_attr)
__global__ void fill_csr(const int* __restrict__ ei, const float* __restrict__ ea,
                         int* __restrict__ curS, int* __restrict__ curD,
                         int* __restrict__ dofs, float* __restrict__ eaperm) {
    int e = blockIdx.x * 256 + threadIdx.x;
    if (e >= NE) return;
    int src = ei[e], dst = ei[NE + e];
    int sslot = atomicAdd(curS + src, 1);
    int dslot = atomicAdd(curD + dst, 1);
    dofs[sslot] = dslot;
    float2 a = ((const float2*)ea)[e];
    ((float2*)eaperm)[sslot] = a;
}

// ================= per-layer kernels =================

// hx = x @ [g | root]  ([N,cin] x [cin,352]) ; 32 nodes/block, transposed LDS tile
template <int CIN>
__global__ __launch_bounds__(384) void gemm_hx(const float* __restrict__ x,
                                               const float* __restrict__ g,
                                               const float* __restrict__ root,
                                               float* __restrict__ hx) {
    __shared__ float xs[CIN][36];
    const int n0 = blockIdx.x * 32;
    const int tid = threadIdx.x;
    for (int idx = tid; idx < 32 * CIN; idx += 384) {
        int i = idx / CIN, c = idx % CIN;
        int n = n0 + i;
        xs[c][i] = (n < NN) ? x[(size_t)n * CIN + c] : 0.0f;
    }
    __syncthreads();
    const int j = tid;
    if (j < HXW) {
        const bool isg = (j < KK * COUT);
        const float* w = isg ? (g + j) : (root + (j - KK * COUT));
        const int ws = isg ? (KK * COUT) : COUT;
        float acc[32];
#pragma unroll
        for (int i = 0; i < 32; i++) acc[i] = 0.0f;
        for (int c = 0; c < CIN; c++) {
            float wv = w[(size_t)c * ws];
            const float4* xr = (const float4*)&xs[c][0];
#pragma unroll
            for (int q = 0; q < 8; q++) {
                float4 v = xr[q];
                acc[4 * q + 0] = fmaf(v.x, wv, acc[4 * q + 0]);
                acc[4 * q + 1] = fmaf(v.y, wv, acc[4 * q + 1]);
                acc[4 * q + 2] = fmaf(v.z, wv, acc[4 * q + 2]);
                acc[4 * q + 3] = fmaf(v.w, wv, acc[4 * q + 3]);
            }
        }
#pragma unroll
        for (int i = 0; i < 32; i++) {
            int n = n0 + i;
            if (n < NN) hx[(size_t)n * HXW + j] = acc[i];
        }
    }
}

// Phase A: per-src wave, h-row once, inline gaussians, write bf16 msg to dst-slot
__global__ __launch_bounds__(256) void msg_kernel(const float* __restrict__ hx,
                                                  const float* __restrict__ eaperm,
                                                  const int* __restrict__ rpS,
                                                  const int* __restrict__ dofs,
                                                  const float* __restrict__ mu,
                                                  const float* __restrict__ sigma,
                                                  __hip_bfloat16* __restrict__ m) {
    float muk[2 * KK], isg[2 * KK];
#pragma unroll
    for (int k = 0; k < 2 * KK; k++) {
        muk[k] = mu[k];
        float sv = sigma[k];
        isg[k] = 1.0f / (EPSV + sv * sv);
    }
    const int tid = threadIdx.x;
    const int wave = tid >> 6, lane = tid & 63;
    const int o = lane & 31, h = lane >> 5;
    const int nwaves = gridDim.x * 4;
    for (int n = blockIdx.x * 4 + wave; n < NN; n += nwaves) {
        const int s0 = rpS[n], s1 = rpS[n + 1];
        if (s0 == s1) continue;
        float hreg[KK];
#pragma unroll
        for (int k = 0; k < KK; k++)
            hreg[k] = hx[(size_t)n * HXW + 32 * k + o];
        for (int s = s0 + h; s < s1; s += 2) {
            int dpos = dofs[s];
            float2 a = ((const float2*)eaperm)[s];
            float acc = 0.0f;
#pragma unroll
            for (int k = 0; k < KK; k++) {
                float d0 = a.x - muk[2 * k];
                float d1 = a.y - muk[2 * k + 1];
                float gv = __expf(-0.5f * (d0 * d0 * isg[2 * k] + d1 * d1 * isg[2 * k + 1]));
                acc = fmaf(gv, hreg[k], acc);
            }
            m[(size_t)dpos * COUT + o] = __float2bfloat16(acc);
        }
    }
}

// Phase B: per-dst wave, contiguous m segment; fused mean + root + bias + elu
__global__ __launch_bounds__(256) void gather_kernel(const __hip_bfloat16* __restrict__ m,
                                                     const int* __restrict__ rpD,
                                                     const float* __restrict__ hx,
                                                     const float* __restrict__ invdeg,
                                                     const float* __restrict__ b,
                                                     float* __restrict__ out) {
    const int tid = threadIdx.x;
    const int wave = tid >> 6, lane = tid & 63;
    const int o = lane & 31, h = lane >> 5;
    const int nwaves = gridDim.x * 4;
    const float bias = b[o];
    for (int n = blockIdx.x * 4 + wave; n < NN; n += nwaves) {
        const int s0 = rpD[n], s1 = rpD[n + 1];
        float acc = 0.0f;
        for (int s = s0 + h; s < s1; s += 2)
            acc += __bfloat162float(m[(size_t)s * COUT + o]);
        acc += __shfl_xor(acc, 32);
        if (h == 0) {
            float v = acc * invdeg[n] + hx[(size_t)n * HXW + KK * COUT + o] + bias;
            out[(size_t)n * COUT + o] = (v > 0.0f) ? v : (__expf(v) - 1.0f);
        }
    }
}

extern "C" void kernel_launch(void* const* d_in, const int* in_sizes, int n_in,
                              void* d_out, int out_size, void* d_ws, size_t ws_size,
                              hipStream_t stream) {
    const float* graph = (const float*)d_in[0];
    const int* ei = (const int*)d_in[1];
    const float* ea = (const float*)d_in[2];
    const float *G[3], *MU[3], *SG[3], *RT[3], *BB[3];
    for (int l = 0; l < 3; l++) {
        G[l]  = (const float*)d_in[3 + 5 * l + 0];
        MU[l] = (const float*)d_in[3 + 5 * l + 1];
        SG[l] = (const float*)d_in[3 + 5 * l + 2];
        RT[l] = (const float*)d_in[3 + 5 * l + 3];
        BB[l] = (const float*)d_in[3 + 5 * l + 4];
    }
    float* out = (float*)d_out;

    // ---- workspace layout ----
    float* hx            = (float*)d_ws;                    // NN*352        = 70.4 MB
    __hip_bfloat16* m    = (__hip_bfloat16*)(hx + (size_t)NN * HXW);  // NE*32 bf16 = 51.2 MB
    float* eaperm        = (float*)(m + (size_t)NE * COUT); // NE*2          = 6.4 MB
    float* invdeg        = eaperm + (size_t)NE * 2;         // NN
    int* dofs            = (int*)(invdeg + NN);             // NE            = 3.2 MB
    int* rpS             = dofs + NE;                       // NN+1
    int* rpD             = rpS + (NN + 1);                  // NN+1
    int* curS            = rpD + (NN + 1);                  // NN
    int* curD            = curS + NN;                       // NN
    int* srcdeg          = curD + NN;                       // NN
    int* dstdeg          = srcdeg + NN;                     // NN
    int* bsumS           = dstdeg + NN;                     // 256
    int* bsumD           = bsumS + 256;                     // 256
    int* bposS           = bsumD + 256;                     // 256
    int* bposD           = bposS + 256;                     // 256

    // ---- CSR build (once) ----
    hipMemsetAsync(srcdeg, 0, 2 * NN * sizeof(int), stream);   // srcdeg+dstdeg contiguous
    count_deg<<<(NE + 255) / 256, 256, 0, stream>>>(ei, srcdeg, dstdeg);
    scan_partial<<<SCAN_NB, 256, 0, stream>>>(srcdeg, dstdeg, bsumS, bsumD);
    scan_blocks<<<1, 256, 0, stream>>>(bsumS, bsumD, bposS, bposD);
    scan_final<<<SCAN_NB, 256, 0, stream>>>(srcdeg, dstdeg, bposS, bposD,
                                            rpS, curS, rpD, curD, invdeg);
    fill_csr<<<(NE + 255) / 256, 256, 0, stream>>>(ei, ea, curS, curD, dofs, eaperm);

    for (int l = 0; l < 3; l++) {
        const float* x = (l == 0) ? graph : (out + (size_t)(l - 1) * NN * COUT);
        if (l == 0)
            gemm_hx<64><<<(NN + 31) / 32, 384, 0, stream>>>(x, G[l], RT[l], hx);
        else
            gemm_hx<32><<<(NN + 31) / 32, 384, 0, stream>>>(x, G[l], RT[l], hx);
        msg_kernel<<<2048, 256, 0, stream>>>(hx, eaperm, rpS, dofs, MU[l], SG[l], m);
        gather_kernel<<<2048, 256, 0, stream>>>(m, rpD, hx, invdeg, BB[l],
                                                out + (size_t)l * NN * COUT);
    }
}

// Round 5
// 663.852 us; speedup vs baseline: 1.0002x; 1.0002x over previous
//
#include <hip/hip_runtime.h>
#include <hip/hip_bf16.h>
#include <math.h>

#define NN 50000
#define NE 800000
#define COUT 32
#define KK 10
#define HCOL 320           // K*OUT  (bf16 h panel width)
#define EPSV 1e-15f
#define SCAN_NB 196        // ceil(50000/256)

// ================= CSR build (once per call) =================

__global__ void count_deg(const int* __restrict__ ei, int* __restrict__ srcdeg,
                          int* __restrict__ dstdeg) {
    int e = blockIdx.x * 256 + threadIdx.x;
    if (e >= NE) return;
    atomicAdd(srcdeg + ei[e], 1);
    atomicAdd(dstdeg + ei[NE + e], 1);
}

__device__ __forceinline__ int block_incl_scan(int v, int* s) {
    int t = threadIdx.x;
    s[t] = v; __syncthreads();
#pragma unroll
    for (int off = 1; off < 256; off <<= 1) {
        int u = (t >= off) ? s[t - off] : 0;
        __syncthreads();
        s[t] += u; __syncthreads();
    }
    int r = s[t]; __syncthreads();
    return r;
}

__global__ __launch_bounds__(256) void scan_partial(const int* __restrict__ srcdeg,
                                                    const int* __restrict__ dstdeg,
                                                    int* __restrict__ bsumS,
                                                    int* __restrict__ bsumD) {
    __shared__ int s[256];
    int i = blockIdx.x * 256 + threadIdx.x;
    int vs = (i < NN) ? srcdeg[i] : 0;
    int vd = (i < NN) ? dstdeg[i] : 0;
    int is = block_incl_scan(vs, s);
    int id = block_incl_scan(vd, s);
    if (threadIdx.x == 255) { bsumS[blockIdx.x] = is; bsumD[blockIdx.x] = id; }
}

__global__ __launch_bounds__(256) void scan_blocks(int* __restrict__ bsumS,
                                                   int* __restrict__ bsumD,
                                                   int* __restrict__ bposS,
                                                   int* __restrict__ bposD) {
    __shared__ int s[256];
    int t = threadIdx.x;
    int vs = (t < SCAN_NB) ? bsumS[t] : 0;
    int vd = (t < SCAN_NB) ? bsumD[t] : 0;
    int is = block_incl_scan(vs, s);
    int id = block_incl_scan(vd, s);
    if (t < SCAN_NB) { bposS[t] = is - vs; bposD[t] = id - vd; }
}

__global__ __launch_bounds__(256) void scan_final(const int* __restrict__ srcdeg,
                                                  const int* __restrict__ dstdeg,
                                                  const int* __restrict__ bposS,
                                                  const int* __restrict__ bposD,
                                                  int* __restrict__ rpS, int* __restrict__ curS,
                                                  int* __restrict__ rpD, int* __restrict__ curD,
                                                  float* __restrict__ invdeg) {
    __shared__ int s[256];
    int i = blockIdx.x * 256 + threadIdx.x;
    int vs = (i < NN) ? srcdeg[i] : 0;
    int vd = (i < NN) ? dstdeg[i] : 0;
    int is = block_incl_scan(vs, s);
    int id = block_incl_scan(vd, s);
    if (i < NN) {
        int es = bposS[blockIdx.x] + is - vs;
        int ed = bposD[blockIdx.x] + id - vd;
        rpS[i] = es; curS[i] = es;
        rpD[i] = ed; curD[i] = ed;
        invdeg[i] = 1.0f / fmaxf((float)vd, 1.0f);
    }
    if (i == NN) { rpS[NN] = NE; rpD[NN] = NE; }
}

// single aligned 8B scattered store per edge: {dst-slot, edge-id}
__global__ void fill_csr(const int* __restrict__ ei,
                         int* __restrict__ curS, int* __restrict__ curD,
                         int2* __restrict__ dperm) {
    int e = blockIdx.x * 256 + threadIdx.x;
    if (e >= NE) return;
    int src = ei[e], dst = ei[NE + e];
    int sslot = atomicAdd(curS + src, 1);
    int dslot = atomicAdd(curD + dst, 1);
    dperm[sslot] = make_int2(dslot, e);
}

// ================= per-layer kernels =================

// hx = x @ [g | root] ; h-panel (320 cols) -> bf16 hxh, root (32 cols) -> fp32 hxr
template <int CIN>
__global__ __launch_bounds__(384) void gemm_hx(const float* __restrict__ x,
                                               const float* __restrict__ g,
                                               const float* __restrict__ root,
                                               __hip_bfloat16* __restrict__ hxh,
                                               float* __restrict__ hxr) {
    __shared__ float xs[CIN][36];
    const int n0 = blockIdx.x * 32;
    const int tid = threadIdx.x;
    for (int idx = tid; idx < 32 * CIN; idx += 384) {
        int i = idx / CIN, c = idx % CIN;
        int n = n0 + i;
        xs[c][i] = (n < NN) ? x[(size_t)n * CIN + c] : 0.0f;
    }
    __syncthreads();
    const int j = tid;
    if (j < HCOL + COUT) {
        const bool isg = (j < HCOL);
        const float* w = isg ? (g + j) : (root + (j - HCOL));
        const int ws = isg ? HCOL : COUT;
        float acc[32];
#pragma unroll
        for (int i = 0; i < 32; i++) acc[i] = 0.0f;
        for (int c = 0; c < CIN; c++) {
            float wv = w[(size_t)c * ws];
            const float4* xr = (const float4*)&xs[c][0];
#pragma unroll
            for (int q = 0; q < 8; q++) {
                float4 v = xr[q];
                acc[4 * q + 0] = fmaf(v.x, wv, acc[4 * q + 0]);
                acc[4 * q + 1] = fmaf(v.y, wv, acc[4 * q + 1]);
                acc[4 * q + 2] = fmaf(v.z, wv, acc[4 * q + 2]);
                acc[4 * q + 3] = fmaf(v.w, wv, acc[4 * q + 3]);
            }
        }
        if (isg) {
#pragma unroll
            for (int i = 0; i < 32; i++) {
                int n = n0 + i;
                if (n < NN) hxh[(size_t)n * HCOL + j] = __float2bfloat16(acc[i]);
            }
        } else {
#pragma unroll
            for (int i = 0; i < 32; i++) {
                int n = n0 + i;
                if (n < NN) hxr[(size_t)n * COUT + (j - HCOL)] = acc[i];
            }
        }
    }
}

// Phase A: per-src wave, bf16 h-row once, inline gaussians, bf16 msg to dst-slot
__global__ __launch_bounds__(256) void msg_kernel(const __hip_bfloat16* __restrict__ hxh,
                                                  const float* __restrict__ ea,
                                                  const int* __restrict__ rpS,
                                                  const int2* __restrict__ dperm,
                                                  const float* __restrict__ mu,
                                                  const float* __restrict__ sigma,
                                                  __hip_bfloat16* __restrict__ m) {
    float muk[2 * KK], isg[2 * KK];
#pragma unroll
    for (int k = 0; k < 2 * KK; k++) {
        muk[k] = mu[k];
        float sv = sigma[k];
        isg[k] = 1.0f / (EPSV + sv * sv);
    }
    const int tid = threadIdx.x;
    const int wave = tid >> 6, lane = tid & 63;
    const int o = lane & 31, h = lane >> 5;
    const int nwaves = gridDim.x * 4;
    for (int n = blockIdx.x * 4 + wave; n < NN; n += nwaves) {
        const int s0 = rpS[n], s1 = rpS[n + 1];
        if (s0 == s1) continue;
        float hreg[KK];
#pragma unroll
        for (int k = 0; k < KK; k++)
            hreg[k] = __bfloat162float(hxh[(size_t)n * HCOL + 32 * k + o]);
        for (int s = s0 + h; s < s1; s += 2) {
            int2 q = dperm[s];
            float2 a = ((const float2*)ea)[q.y];
            float acc = 0.0f;
#pragma unroll
            for (int k = 0; k < KK; k++) {
                float d0 = a.x - muk[2 * k];
                float d1 = a.y - muk[2 * k + 1];
                float gv = __expf(-0.5f * (d0 * d0 * isg[2 * k] + d1 * d1 * isg[2 * k + 1]));
                acc = fmaf(gv, hreg[k], acc);
            }
            m[(size_t)q.x * COUT + o] = __float2bfloat16(acc);
        }
    }
}

// Phase B: per-dst wave, packed uint reads (2 bf16/lane), 4 rows/iter; fused epilogue
__global__ __launch_bounds__(256) void gather_kernel(const __hip_bfloat16* __restrict__ m,
                                                     const int* __restrict__ rpD,
                                                     const float* __restrict__ hxr,
                                                     const float* __restrict__ invdeg,
                                                     const float* __restrict__ b,
                                                     float* __restrict__ out) {
    const int tid = threadIdx.x;
    const int wave = tid >> 6, lane = tid & 63;
    const int p = lane & 15;        // uint slot: outputs 2p, 2p+1
    const int h = lane >> 4;        // 0..3
    const int nwaves = gridDim.x * 4;
    const float b0 = b[2 * p], b1 = b[2 * p + 1];
    for (int n = blockIdx.x * 4 + wave; n < NN; n += nwaves) {
        const int s0 = rpD[n], s1 = rpD[n + 1];
        float a0 = 0.0f, a1 = 0.0f;
        for (int s = s0 + h; s < s1; s += 4) {
            unsigned int v = ((const unsigned int*)m)[(size_t)s * 16 + p];
            a0 += __uint_as_float(v << 16);
            a1 += __uint_as_float(v & 0xffff0000u);
        }
        a0 += __shfl_xor(a0, 16); a1 += __shfl_xor(a1, 16);
        a0 += __shfl_xor(a0, 32); a1 += __shfl_xor(a1, 32);
        if (h == 0) {
            float inv = invdeg[n];
            float2 r = ((const float2*)hxr)[(size_t)n * 16 + p];
            float v0 = a0 * inv + r.x + b0;
            float v1 = a1 * inv + r.y + b1;
            v0 = (v0 > 0.0f) ? v0 : (__expf(v0) - 1.0f);
            v1 = (v1 > 0.0f) ? v1 : (__expf(v1) - 1.0f);
            ((float2*)out)[(size_t)n * 16 + p] = make_float2(v0, v1);
        }
    }
}

extern "C" void kernel_launch(void* const* d_in, const int* in_sizes, int n_in,
                              void* d_out, int out_size, void* d_ws, size_t ws_size,
                              hipStream_t stream) {
    const float* graph = (const float*)d_in[0];
    const int* ei = (const int*)d_in[1];
    const float* ea = (const float*)d_in[2];
    const float *G[3], *MU[3], *SG[3], *RT[3], *BB[3];
    for (int l = 0; l < 3; l++) {
        G[l]  = (const float*)d_in[3 + 5 * l + 0];
        MU[l] = (const float*)d_in[3 + 5 * l + 1];
        SG[l] = (const float*)d_in[3 + 5 * l + 2];
        RT[l] = (const float*)d_in[3 + 5 * l + 3];
        BB[l] = (const float*)d_in[3 + 5 * l + 4];
    }
    float* out = (float*)d_out;

    // ---- workspace layout ----
    char* w = (char*)d_ws;
    __hip_bfloat16* hxh = (__hip_bfloat16*)w;           w += (size_t)NN * HCOL * 2;   // 32.0 MB
    float* hxr          = (float*)w;                    w += (size_t)NN * COUT * 4;   //  6.4 MB
    __hip_bfloat16* m   = (__hip_bfloat16*)w;           w += (size_t)NE * COUT * 2;   // 51.2 MB
    int2* dperm         = (int2*)w;                     w += (size_t)NE * 8;          //  6.4 MB
    float* invdeg       = (float*)w;                    w += (size_t)NN * 4;
    int* rpS            = (int*)w;                      w += (size_t)(NN + 1) * 4;
    int* rpD            = (int*)w;                      w += (size_t)(NN + 1) * 4;
    int* curS           = (int*)w;                      w += (size_t)NN * 4;
    int* curD           = (int*)w;                      w += (size_t)NN * 4;
    int* srcdeg         = (int*)w;                      w += (size_t)NN * 4;
    int* dstdeg         = (int*)w;                      w += (size_t)NN * 4;
    int* bsumS          = (int*)w;                      w += 256 * 4;
    int* bsumD          = (int*)w;                      w += 256 * 4;
    int* bposS          = (int*)w;                      w += 256 * 4;
    int* bposD          = (int*)w;                      w += 256 * 4;

    // ---- CSR build (once) ----
    hipMemsetAsync(srcdeg, 0, 2 * NN * sizeof(int), stream);   // srcdeg+dstdeg contiguous
    count_deg<<<(NE + 255) / 256, 256, 0, stream>>>(ei, srcdeg, dstdeg);
    scan_partial<<<SCAN_NB, 256, 0, stream>>>(srcdeg, dstdeg, bsumS, bsumD);
    scan_blocks<<<1, 256, 0, stream>>>(bsumS, bsumD, bposS, bposD);
    scan_final<<<SCAN_NB, 256, 0, stream>>>(srcdeg, dstdeg, bposS, bposD,
                                            rpS, curS, rpD, curD, invdeg);
    fill_csr<<<(NE + 255) / 256, 256, 0, stream>>>(ei, curS, curD, dperm);

    for (int l = 0; l < 3; l++) {
        const float* x = (l == 0) ? graph : (out + (size_t)(l - 1) * NN * COUT);
        if (l == 0)
            gemm_hx<64><<<(NN + 31) / 32, 384, 0, stream>>>(x, G[l], RT[l], hxh, hxr);
        else
            gemm_hx<32><<<(NN + 31) / 32, 384, 0, stream>>>(x, G[l], RT[l], hxh, hxr);
        msg_kernel<<<2048, 256, 0, stream>>>(hxh, ea, rpS, dperm, MU[l], SG[l], m);
        gather_kernel<<<2048, 256, 0, stream>>>(m, rpD, hxr, invdeg, BB[l],
                                                out + (size_t)l * NN * COUT);
    }
}

// Round 7
// 537.166 us; speedup vs baseline: 1.2361x; 1.2358x over previous
//
#include <hip/hip_runtime.h>
#include <hip/hip_bf16.h>
#include <math.h>

#define NN 50000
#define NE 800000
#define COUT 32
#define KK 10
#define HCOL 320           // K*OUT  (bf16 h panel width)
#define EPSV 1e-15f
#define SCAN_NB 196        // ceil(50000/256)

// ================= CSR build (once per call) =================
// rank pass: one atomic per edge, coalesced result write; counters become degrees
__global__ void rank_src(const int* __restrict__ ei, int* __restrict__ curS,
                         int* __restrict__ rankS) {
    int e = blockIdx.x * 256 + threadIdx.x;
    if (e >= NE) return;
    rankS[e] = atomicAdd(curS + ei[e], 1);
}

__global__ void rank_dst(const int* __restrict__ ei, int* __restrict__ curD,
                         int* __restrict__ rankD) {
    int e = blockIdx.x * 256 + threadIdx.x;
    if (e >= NE) return;
    rankD[e] = atomicAdd(curD + ei[NE + e], 1);
}

__device__ __forceinline__ int block_incl_scan(int v, int* s) {
    int t = threadIdx.x;
    s[t] = v; __syncthreads();
#pragma unroll
    for (int off = 1; off < 256; off <<= 1) {
        int u = (t >= off) ? s[t - off] : 0;
        __syncthreads();
        s[t] += u; __syncthreads();
    }
    int r = s[t]; __syncthreads();
    return r;
}

__global__ __launch_bounds__(256) void scan_partial(const int* __restrict__ degS,
                                                    const int* __restrict__ degD,
                                                    int* __restrict__ bsumS,
                                                    int* __restrict__ bsumD) {
    __shared__ int s[256];
    int i = blockIdx.x * 256 + threadIdx.x;
    int vs = (i < NN) ? degS[i] : 0;
    int vd = (i < NN) ? degD[i] : 0;
    int is = block_incl_scan(vs, s);
    int id = block_incl_scan(vd, s);
    if (threadIdx.x == 255) { bsumS[blockIdx.x] = is; bsumD[blockIdx.x] = id; }
}

__global__ __launch_bounds__(256) void scan_blocks(int* __restrict__ bsumS,
                                                   int* __restrict__ bsumD,
                                                   int* __restrict__ bposS,
                                                   int* __restrict__ bposD) {
    __shared__ int s[256];
    int t = threadIdx.x;
    int vs = (t < SCAN_NB) ? bsumS[t] : 0;
    int vd = (t < SCAN_NB) ? bsumD[t] : 0;
    int is = block_incl_scan(vs, s);
    int id = block_incl_scan(vd, s);
    if (t < SCAN_NB) { bposS[t] = is - vs; bposD[t] = id - vd; }
}

__global__ __launch_bounds__(256) void scan_final(const int* __restrict__ degS,
                                                  const int* __restrict__ degD,
                                                  const int* __restrict__ bposS,
                                                  const int* __restrict__ bposD,
                                                  int* __restrict__ rpS,
                                                  int* __restrict__ rpD,
                                                  float* __restrict__ invdeg) {
    __shared__ int s[256];
    int i = blockIdx.x * 256 + threadIdx.x;
    int vs = (i < NN) ? degS[i] : 0;
    int vd = (i < NN) ? degD[i] : 0;
    int is = block_incl_scan(vs, s);
    int id = block_incl_scan(vd, s);
    if (i < NN) {
        rpS[i] = bposS[blockIdx.x] + is - vs;
        rpD[i] = bposD[blockIdx.x] + id - vd;
        invdeg[i] = 1.0f / fmaxf((float)vd, 1.0f);
    }
    if (i == NN) { rpS[NN] = NE; rpD[NN] = NE; }
}

// atomic-free permutation scatter: one aligned 16B store per edge
__global__ void scatter_perm(const int* __restrict__ ei, const float* __restrict__ ea,
                             const int* __restrict__ rankS, const int* __restrict__ rankD,
                             const int* __restrict__ rpS, const int* __restrict__ rpD,
                             float4* __restrict__ dperm) {
    int e = blockIdx.x * 256 + threadIdx.x;
    if (e >= NE) return;
    int src = ei[e], dst = ei[NE + e];
    int sslot = rpS[src] + rankS[e];
    int dslot = rpD[dst] + rankD[e];
    float2 a = ((const float2*)ea)[e];
    dperm[sslot] = make_float4(__int_as_float(dslot), 0.0f, a.x, a.y);
}

// ================= per-layer kernels =================

// hx = x @ [g | root] ; h-panel (320 cols) -> bf16 hxh, root (32 cols) -> fp32 hxr
template <int CIN>
__global__ __launch_bounds__(384) void gemm_hx(const float* __restrict__ x,
                                               const float* __restrict__ g,
                                               const float* __restrict__ root,
                                               __hip_bfloat16* __restrict__ hxh,
                                               float* __restrict__ hxr) {
    __shared__ float xs[CIN][36];
    const int n0 = blockIdx.x * 32;
    const int tid = threadIdx.x;
    for (int idx = tid; idx < 32 * CIN; idx += 384) {
        int i = idx / CIN, c = idx % CIN;
        int n = n0 + i;
        xs[c][i] = (n < NN) ? x[(size_t)n * CIN + c] : 0.0f;
    }
    __syncthreads();
    const int j = tid;
    if (j < HCOL + COUT) {
        const bool isg = (j < HCOL);
        const float* w = isg ? (g + j) : (root + (j - HCOL));
        const int ws = isg ? HCOL : COUT;
        float acc[32];
#pragma unroll
        for (int i = 0; i < 32; i++) acc[i] = 0.0f;
        for (int c = 0; c < CIN; c++) {
            float wv = w[(size_t)c * ws];
            const float4* xr = (const float4*)&xs[c][0];
#pragma unroll
            for (int q = 0; q < 8; q++) {
                float4 v = xr[q];
                acc[4 * q + 0] = fmaf(v.x, wv, acc[4 * q + 0]);
                acc[4 * q + 1] = fmaf(v.y, wv, acc[4 * q + 1]);
                acc[4 * q + 2] = fmaf(v.z, wv, acc[4 * q + 2]);
                acc[4 * q + 3] = fmaf(v.w, wv, acc[4 * q + 3]);
            }
        }
        if (isg) {
#pragma unroll
            for (int i = 0; i < 32; i++) {
                int n = n0 + i;
                if (n < NN) hxh[(size_t)n * HCOL + j] = __float2bfloat16(acc[i]);
            }
        } else {
#pragma unroll
            for (int i = 0; i < 32; i++) {
                int n = n0 + i;
                if (n < NN) hxr[(size_t)n * COUT + (j - HCOL)] = acc[i];
            }
        }
    }
}

// Phase A: per-src wave, bf16 h-row once, inline gaussians; fully streaming I/O
__global__ __launch_bounds__(256) void msg_kernel(const __hip_bfloat16* __restrict__ hxh,
                                                  const int* __restrict__ rpS,
                                                  const float4* __restrict__ dperm,
                                                  const float* __restrict__ mu,
                                                  const float* __restrict__ sigma,
                                                  __hip_bfloat16* __restrict__ m) {
    float muk[2 * KK], isg[2 * KK];
#pragma unroll
    for (int k = 0; k < 2 * KK; k++) {
        muk[k] = mu[k];
        float sv = sigma[k];
        isg[k] = 1.0f / (EPSV + sv * sv);
    }
    const int tid = threadIdx.x;
    const int wave = tid >> 6, lane = tid & 63;
    const int o = lane & 31, h = lane >> 5;
    const int nwaves = gridDim.x * 4;
    for (int n = blockIdx.x * 4 + wave; n < NN; n += nwaves) {
        const int s0 = rpS[n], s1 = rpS[n + 1];
        if (s0 == s1) continue;
        float hreg[KK];
#pragma unroll
        for (int k = 0; k < KK; k++)
            hreg[k] = __bfloat162float(hxh[(size_t)n * HCOL + 32 * k + o]);
        for (int s = s0 + h; s < s1; s += 2) {
            float4 q = dperm[s];
            int dpos = __float_as_int(q.x);
            float acc = 0.0f;
#pragma unroll
            for (int k = 0; k < KK; k++) {
                float d0 = q.z - muk[2 * k];
                float d1 = q.w - muk[2 * k + 1];
                float gv = __expf(-0.5f * (d0 * d0 * isg[2 * k] + d1 * d1 * isg[2 * k + 1]));
                acc = fmaf(gv, hreg[k], acc);
            }
            m[(size_t)dpos * COUT + o] = __float2bfloat16(acc);
        }
    }
}

// Phase B: per-dst wave, packed uint reads (2 bf16/lane), 4 rows/iter; fused epilogue
__global__ __launch_bounds__(256) void gather_kernel(const __hip_bfloat16* __restrict__ m,
                                                     const int* __restrict__ rpD,
                                                     const float* __restrict__ hxr,
                                                     const float* __restrict__ invdeg,
                                                     const float* __restrict__ b,
                                                     float* __restrict__ out) {
    const int tid = threadIdx.x;
    const int wave = tid >> 6, lane = tid & 63;
    const int p = lane & 15;        // uint slot: outputs 2p, 2p+1
    const int h = lane >> 4;        // 0..3
    const int nwaves = gridDim.x * 4;
    const float b0 = b[2 * p], b1 = b[2 * p + 1];
    for (int n = blockIdx.x * 4 + wave; n < NN; n += nwaves) {
        const int s0 = rpD[n], s1 = rpD[n + 1];
        float a0 = 0.0f, a1 = 0.0f;
        for (int s = s0 + h; s < s1; s += 4) {
            unsigned int v = ((const unsigned int*)m)[(size_t)s * 16 + p];
            a0 += __uint_as_float(v << 16);
            a1 += __uint_as_float(v & 0xffff0000u);
        }
        a0 += __shfl_xor(a0, 16); a1 += __shfl_xor(a1, 16);
        a0 += __shfl_xor(a0, 32); a1 += __shfl_xor(a1, 32);
        if (h == 0) {
            float inv = invdeg[n];
            float2 r = ((const float2*)hxr)[(size_t)n * 16 + p];
            float v0 = a0 * inv + r.x + b0;
            float v1 = a1 * inv + r.y + b1;
            v0 = (v0 > 0.0f) ? v0 : (__expf(v0) - 1.0f);
            v1 = (v1 > 0.0f) ? v1 : (__expf(v1) - 1.0f);
            ((float2*)out)[(size_t)n * 16 + p] = make_float2(v0, v1);
        }
    }
}

extern "C" void kernel_launch(void* const* d_in, const int* in_sizes, int n_in,
                              void* d_out, int out_size, void* d_ws, size_t ws_size,
                              hipStream_t stream) {
    const float* graph = (const float*)d_in[0];
    const int* ei = (const int*)d_in[1];
    const float* ea = (const float*)d_in[2];
    const float *G[3], *MU[3], *SG[3], *RT[3], *BB[3];
    for (int l = 0; l < 3; l++) {
        G[l]  = (const float*)d_in[3 + 5 * l + 0];
        MU[l] = (const float*)d_in[3 + 5 * l + 1];
        SG[l] = (const float*)d_in[3 + 5 * l + 2];
        RT[l] = (const float*)d_in[3 + 5 * l + 3];
        BB[l] = (const float*)d_in[3 + 5 * l + 4];
    }
    float* out = (float*)d_out;

    // ---- workspace layout (16B-aligned chunks first) ----
    char* w = (char*)d_ws;
    __hip_bfloat16* hxh = (__hip_bfloat16*)w;   w += (size_t)NN * HCOL * 2;   // 32.0 MB
    float* hxr          = (float*)w;            w += (size_t)NN * COUT * 4;   //  6.4 MB
    __hip_bfloat16* m   = (__hip_bfloat16*)w;   w += (size_t)NE * COUT * 2;   // 51.2 MB
    float4* dperm       = (float4*)w;           w += (size_t)NE * 16;         // 12.8 MB
    int* rankS          = (int*)w;              w += (size_t)NE * 4;          //  3.2 MB
    int* rankD          = (int*)w;              w += (size_t)NE * 4;          //  3.2 MB
    float* invdeg       = (float*)w;            w += (size_t)NN * 4;
    int* rpS            = (int*)w;              w += (size_t)(NN + 1) * 4;
    int* rpD            = (int*)w;              w += (size_t)(NN + 1) * 4;
    int* curS           = (int*)w;              w += (size_t)NN * 4;
    int* curD           = (int*)w;              w += (size_t)NN * 4;   // curS,curD contiguous
    int* bsumS          = (int*)w;              w += 256 * 4;
    int* bsumD          = (int*)w;              w += 256 * 4;
    int* bposS          = (int*)w;              w += 256 * 4;
    int* bposD          = (int*)w;              w += 256 * 4;

    // ---- CSR build (once): rank -> scan -> atomic-free scatter ----
    hipMemsetAsync(curS, 0, 2 * NN * sizeof(int), stream);
    rank_src<<<(NE + 255) / 256, 256, 0, stream>>>(ei, curS, rankS);
    rank_dst<<<(NE + 255) / 256, 256, 0, stream>>>(ei, curD, rankD);
    scan_partial<<<SCAN_NB, 256, 0, stream>>>(curS, curD, bsumS, bsumD);
    scan_blocks<<<1, 256, 0, stream>>>(bsumS, bsumD, bposS, bposD);
    scan_final<<<SCAN_NB, 256, 0, stream>>>(curS, curD, bposS, bposD, rpS, rpD, invdeg);
    scatter_perm<<<(NE + 255) / 256, 256, 0, stream>>>(ei, ea, rankS, rankD, rpS, rpD, dperm);

    for (int l = 0; l < 3; l++) {
        const float* x = (l == 0) ? graph : (out + (size_t)(l - 1) * NN * COUT);
        if (l == 0)
            gemm_hx<64><<<(NN + 31) / 32, 384, 0, stream>>>(x, G[l], RT[l], hxh, hxr);
        else
            gemm_hx<32><<<(NN + 31) / 32, 384, 0, stream>>>(x, G[l], RT[l], hxh, hxr);
        msg_kernel<<<2048, 256, 0, stream>>>(hxh, rpS, dperm, MU[l], SG[l], m);
        gather_kernel<<<2048, 256, 0, stream>>>(m, rpD, hxr, invdeg, BB[l],
                                                out + (size_t)l * NN * COUT);
    }
}

// Round 8
// 380.354 us; speedup vs baseline: 1.7457x; 1.4123x over previous
//
#include <hip/hip_runtime.h>
#include <hip/hip_bf16.h>
#include <math.h>

#define NN 50000
#define NE 800000
#define COUT 32
#define KK 10
#define HCOL 320           // K*OUT  (bf16 h panel width)
#define EPSV 1e-15f
#define SCAN_NB 196        // ceil(50000/256)
#define MBATCH 64          // msg edge batch per wave

// ================= CSR build (once per call) =================
// rank pass: two atomics per edge, coalesced result writes; counters become degrees
__global__ void rank_edges(const int* __restrict__ ei, int* __restrict__ curS,
                           int* __restrict__ curD, int* __restrict__ rankS,
                           int* __restrict__ rankD) {
    int e = blockIdx.x * 256 + threadIdx.x;
    if (e >= NE) return;
    rankS[e] = atomicAdd(curS + ei[e], 1);
    rankD[e] = atomicAdd(curD + ei[NE + e], 1);
}

__device__ __forceinline__ int block_incl_scan(int v, int* s) {
    int t = threadIdx.x;
    s[t] = v; __syncthreads();
#pragma unroll
    for (int off = 1; off < 256; off <<= 1) {
        int u = (t >= off) ? s[t - off] : 0;
        __syncthreads();
        s[t] += u; __syncthreads();
    }
    int r = s[t]; __syncthreads();
    return r;
}

__global__ __launch_bounds__(256) void scan_partial(const int* __restrict__ degS,
                                                    const int* __restrict__ degD,
                                                    int* __restrict__ bsumS,
                                                    int* __restrict__ bsumD) {
    __shared__ int s[256];
    int i = blockIdx.x * 256 + threadIdx.x;
    int vs = (i < NN) ? degS[i] : 0;
    int vd = (i < NN) ? degD[i] : 0;
    int is = block_incl_scan(vs, s);
    int id = block_incl_scan(vd, s);
    if (threadIdx.x == 255) { bsumS[blockIdx.x] = is; bsumD[blockIdx.x] = id; }
}

__global__ __launch_bounds__(256) void scan_blocks(int* __restrict__ bsumS,
                                                   int* __restrict__ bsumD,
                                                   int* __restrict__ bposS,
                                                   int* __restrict__ bposD) {
    __shared__ int s[256];
    int t = threadIdx.x;
    int vs = (t < SCAN_NB) ? bsumS[t] : 0;
    int vd = (t < SCAN_NB) ? bsumD[t] : 0;
    int is = block_incl_scan(vs, s);
    int id = block_incl_scan(vd, s);
    if (t < SCAN_NB) { bposS[t] = is - vs; bposD[t] = id - vd; }
}

__global__ __launch_bounds__(256) void scan_final(const int* __restrict__ degS,
                                                  const int* __restrict__ degD,
                                                  const int* __restrict__ bposS,
                                                  const int* __restrict__ bposD,
                                                  int* __restrict__ rpS,
                                                  int* __restrict__ rpD,
                                                  float* __restrict__ invdeg) {
    __shared__ int s[256];
    int i = blockIdx.x * 256 + threadIdx.x;
    int vs = (i < NN) ? degS[i] : 0;
    int vd = (i < NN) ? degD[i] : 0;
    int is = block_incl_scan(vs, s);
    int id = block_incl_scan(vd, s);
    if (i < NN) {
        rpS[i] = bposS[blockIdx.x] + is - vs;
        rpD[i] = bposD[blockIdx.x] + id - vd;
        invdeg[i] = 1.0f / fmaxf((float)vd, 1.0f);
    }
    if (i == NN) { rpS[NN] = NE; rpD[NN] = NE; }
}

// atomic-free permutation scatter: one aligned 16B store per edge
__global__ void scatter_perm(const int* __restrict__ ei, const float* __restrict__ ea,
                             const int* __restrict__ rankS, const int* __restrict__ rankD,
                             const int* __restrict__ rpS, const int* __restrict__ rpD,
                             float4* __restrict__ dperm) {
    int e = blockIdx.x * 256 + threadIdx.x;
    if (e >= NE) return;
    int src = ei[e], dst = ei[NE + e];
    int sslot = rpS[src] + rankS[e];
    int dslot = rpD[dst] + rankD[e];
    float2 a = ((const float2*)ea)[e];
    dperm[sslot] = make_float4(__int_as_float(dslot), 0.0f, a.x, a.y);
}

// ================= per-layer kernels =================

// hx = x @ [g | root] ; h-panel (320 cols) -> bf16 hxh, root (32 cols) -> fp32 hxr
template <int CIN>
__global__ __launch_bounds__(384) void gemm_hx(const float* __restrict__ x,
                                               const float* __restrict__ g,
                                               const float* __restrict__ root,
                                               __hip_bfloat16* __restrict__ hxh,
                                               float* __restrict__ hxr) {
    __shared__ float xs[CIN][36];
    const int n0 = blockIdx.x * 32;
    const int tid = threadIdx.x;
    for (int idx = tid; idx < 32 * CIN; idx += 384) {
        int i = idx / CIN, c = idx % CIN;
        int n = n0 + i;
        xs[c][i] = (n < NN) ? x[(size_t)n * CIN + c] : 0.0f;
    }
    __syncthreads();
    const int j = tid;
    if (j < HCOL + COUT) {
        const bool isg = (j < HCOL);
        const float* w = isg ? (g + j) : (root + (j - HCOL));
        const int ws = isg ? HCOL : COUT;
        float acc[32];
#pragma unroll
        for (int i = 0; i < 32; i++) acc[i] = 0.0f;
        for (int c = 0; c < CIN; c++) {
            float wv = w[(size_t)c * ws];
            const float4* xr = (const float4*)&xs[c][0];
#pragma unroll
            for (int q = 0; q < 8; q++) {
                float4 v = xr[q];
                acc[4 * q + 0] = fmaf(v.x, wv, acc[4 * q + 0]);
                acc[4 * q + 1] = fmaf(v.y, wv, acc[4 * q + 1]);
                acc[4 * q + 2] = fmaf(v.z, wv, acc[4 * q + 2]);
                acc[4 * q + 3] = fmaf(v.w, wv, acc[4 * q + 3]);
            }
        }
        if (isg) {
#pragma unroll
            for (int i = 0; i < 32; i++) {
                int n = n0 + i;
                if (n < NN) hxh[(size_t)n * HCOL + j] = __float2bfloat16(acc[i]);
            }
        } else {
#pragma unroll
            for (int i = 0; i < 32; i++) {
                int n = n0 + i;
                if (n < NN) hxr[(size_t)n * COUT + (j - HCOL)] = acc[i];
            }
        }
    }
}

// Phase A: per-src wave; per 64-edge batch: lane j computes edge j's 10 gaussians
// ONCE into LDS, then halves stream edges with broadcast b128 reads + 10 FMA.
__global__ __launch_bounds__(256) void msg_kernel(const __hip_bfloat16* __restrict__ hxh,
                                                  const int* __restrict__ rpS,
                                                  const float4* __restrict__ dperm,
                                                  const float* __restrict__ mu,
                                                  const float* __restrict__ sigma,
                                                  __hip_bfloat16* __restrict__ m) {
    __shared__ float gws[4][MBATCH][12];     // 12 KB: [wave][edge][10 gw, dpos, pad]
    float muk[2 * KK], isg[2 * KK];
#pragma unroll
    for (int k = 0; k < 2 * KK; k++) {
        muk[k] = mu[k];
        float sv = sigma[k];
        isg[k] = 1.0f / (EPSV + sv * sv);
    }
    const int tid = threadIdx.x;
    const int wave = tid >> 6, lane = tid & 63;
    const int o = lane & 31, h = lane >> 5;
    const int nwaves = gridDim.x * 4;
    for (int n = blockIdx.x * 4 + wave; n < NN; n += nwaves) {
        const int s0 = rpS[n], s1 = rpS[n + 1];
        if (s0 == s1) continue;
        float hreg[KK];
#pragma unroll
        for (int k = 0; k < KK; k++)
            hreg[k] = __bfloat162float(hxh[(size_t)n * HCOL + 32 * k + o]);
        for (int base = s0; base < s1; base += MBATCH) {
            const int cnt = min(MBATCH, s1 - base);
            if (lane < cnt) {                       // phase 1: one edge per lane
                float4 q = dperm[base + lane];
                float wv[12];
#pragma unroll
                for (int k = 0; k < KK; k++) {
                    float d0 = q.z - muk[2 * k];
                    float d1 = q.w - muk[2 * k + 1];
                    wv[k] = __expf(-0.5f * (d0 * d0 * isg[2 * k] + d1 * d1 * isg[2 * k + 1]));
                }
                wv[10] = q.x;                       // dpos bits
                wv[11] = 0.0f;
                float4* row = (float4*)gws[wave][lane];
                row[0] = make_float4(wv[0], wv[1], wv[2], wv[3]);
                row[1] = make_float4(wv[4], wv[5], wv[6], wv[7]);
                row[2] = make_float4(wv[8], wv[9], wv[10], wv[11]);
            }
            __threadfence_block();                  // drain ds_writes (wave-private LDS)
            for (int j = h; j < cnt; j += 2) {      // phase 2: 2 edges per wave-iter
                const float4* row = (const float4*)gws[wave][j];
                float4 g0 = row[0], g1 = row[1], g2 = row[2];
                int dpos = __float_as_int(g2.z);
                float acc = g0.x * hreg[0] + g0.y * hreg[1] + g0.z * hreg[2] + g0.w * hreg[3]
                          + g1.x * hreg[4] + g1.y * hreg[5] + g1.z * hreg[6] + g1.w * hreg[7]
                          + g2.x * hreg[8] + g2.y * hreg[9];
                m[(size_t)dpos * COUT + o] = __float2bfloat16(acc);
            }
            __threadfence_block();                  // reads done before next batch overwrites
        }
    }
}

// Phase B: per-dst wave, packed uint reads (2 bf16/lane), 4 rows/iter; fused epilogue
__global__ __launch_bounds__(256) void gather_kernel(const __hip_bfloat16* __restrict__ m,
                                                     const int* __restrict__ rpD,
                                                     const float* __restrict__ hxr,
                                                     const float* __restrict__ invdeg,
                                                     const float* __restrict__ b,
                                                     float* __restrict__ out) {
    const int tid = threadIdx.x;
    const int wave = tid >> 6, lane = tid & 63;
    const int p = lane & 15;        // uint slot: outputs 2p, 2p+1
    const int h = lane >> 4;        // 0..3
    const int nwaves = gridDim.x * 4;
    const float b0 = b[2 * p], b1 = b[2 * p + 1];
    for (int n = blockIdx.x * 4 + wave; n < NN; n += nwaves) {
        const int s0 = rpD[n], s1 = rpD[n + 1];
        float a0 = 0.0f, a1 = 0.0f;
        for (int s = s0 + h; s < s1; s += 4) {
            unsigned int v = ((const unsigned int*)m)[(size_t)s * 16 + p];
            a0 += __uint_as_float(v << 16);
            a1 += __uint_as_float(v & 0xffff0000u);
        }
        a0 += __shfl_xor(a0, 16); a1 += __shfl_xor(a1, 16);
        a0 += __shfl_xor(a0, 32); a1 += __shfl_xor(a1, 32);
        if (h == 0) {
            float inv = invdeg[n];
            float2 r = ((const float2*)hxr)[(size_t)n * 16 + p];
            float v0 = a0 * inv + r.x + b0;
            float v1 = a1 * inv + r.y + b1;
            v0 = (v0 > 0.0f) ? v0 : (__expf(v0) - 1.0f);
            v1 = (v1 > 0.0f) ? v1 : (__expf(v1) - 1.0f);
            ((float2*)out)[(size_t)n * 16 + p] = make_float2(v0, v1);
        }
    }
}

extern "C" void kernel_launch(void* const* d_in, const int* in_sizes, int n_in,
                              void* d_out, int out_size, void* d_ws, size_t ws_size,
                              hipStream_t stream) {
    const float* graph = (const float*)d_in[0];
    const int* ei = (const int*)d_in[1];
    const float* ea = (const float*)d_in[2];
    const float *G[3], *MU[3], *SG[3], *RT[3], *BB[3];
    for (int l = 0; l < 3; l++) {
        G[l]  = (const float*)d_in[3 + 5 * l + 0];
        MU[l] = (const float*)d_in[3 + 5 * l + 1];
        SG[l] = (const float*)d_in[3 + 5 * l + 2];
        RT[l] = (const float*)d_in[3 + 5 * l + 3];
        BB[l] = (const float*)d_in[3 + 5 * l + 4];
    }
    float* out = (float*)d_out;

    // ---- workspace layout (16B-aligned chunks first) ----
    char* w = (char*)d_ws;
    __hip_bfloat16* hxh = (__hip_bfloat16*)w;   w += (size_t)NN * HCOL * 2;   // 32.0 MB
    float* hxr          = (float*)w;            w += (size_t)NN * COUT * 4;   //  6.4 MB
    __hip_bfloat16* m   = (__hip_bfloat16*)w;   w += (size_t)NE * COUT * 2;   // 51.2 MB
    float4* dperm       = (float4*)w;           w += (size_t)NE * 16;         // 12.8 MB
    int* rankS          = (int*)w;              w += (size_t)NE * 4;          //  3.2 MB
    int* rankD          = (int*)w;              w += (size_t)NE * 4;          //  3.2 MB
    float* invdeg       = (float*)w;            w += (size_t)NN * 4;
    int* rpS            = (int*)w;              w += (size_t)(NN + 1) * 4;
    int* rpD            = (int*)w;              w += (size_t)(NN + 1) * 4;
    int* curS           = (int*)w;              w += (size_t)NN * 4;
    int* curD           = (int*)w;              w += (size_t)NN * 4;   // curS,curD contiguous
    int* bsumS          = (int*)w;              w += 256 * 4;
    int* bsumD          = (int*)w;              w += 256 * 4;
    int* bposS          = (int*)w;              w += 256 * 4;
    int* bposD          = (int*)w;              w += 256 * 4;

    // ---- CSR build (once): rank -> scan -> atomic-free scatter ----
    hipMemsetAsync(curS, 0, 2 * NN * sizeof(int), stream);
    rank_edges<<<(NE + 255) / 256, 256, 0, stream>>>(ei, curS, curD, rankS, rankD);
    scan_partial<<<SCAN_NB, 256, 0, stream>>>(curS, curD, bsumS, bsumD);
    scan_blocks<<<1, 256, 0, stream>>>(bsumS, bsumD, bposS, bposD);
    scan_final<<<SCAN_NB, 256, 0, stream>>>(curS, curD, bposS, bposD, rpS, rpD, invdeg);
    scatter_perm<<<(NE + 255) / 256, 256, 0, stream>>>(ei, ea, rankS, rankD, rpS, rpD, dperm);

    for (int l = 0; l < 3; l++) {
        const float* x = (l == 0) ? graph : (out + (size_t)(l - 1) * NN * COUT);
        if (l == 0)
            gemm_hx<64><<<(NN + 31) / 32, 384, 0, stream>>>(x, G[l], RT[l], hxh, hxr);
        else
            gemm_hx<32><<<(NN + 31) / 32, 384, 0, stream>>>(x, G[l], RT[l], hxh, hxr);
        msg_kernel<<<2048, 256, 0, stream>>>(hxh, rpS, dperm, MU[l], SG[l], m);
        gather_kernel<<<2048, 256, 0, stream>>>(m, rpD, hxr, invdeg, BB[l],
                                                out + (size_t)l * NN * COUT);
    }
}

// Round 9
// 376.134 us; speedup vs baseline: 1.7653x; 1.0112x over previous
//
#include <hip/hip_runtime.h>
#include <hip/hip_bf16.h>
#include <math.h>

#define NN 50000
#define NE 800000
#define COUT 32
#define KK 10
#define HCOL 320           // K*OUT  (bf16 h panel width)
#define EPSV 1e-15f
#define SCAN_NB 196        // ceil(50000/256)
#define MBATCH 64          // msg edge batch per wave
#define NREP 4             // counter replicas (contention spread + ILP)

// ================= CSR build (once per call) =================
// rank pass: 4 edges/thread, replica-split counters; ushort2 local ranks
__global__ __launch_bounds__(256) void rank_edges(const int* __restrict__ ei,
                                                  int* __restrict__ cntS,
                                                  int* __restrict__ cntD,
                                                  ushort2* __restrict__ rankL) {
    const int base = blockIdx.x * (NREP * 256);
    const int t = threadIdx.x;
#pragma unroll
    for (int i = 0; i < NREP; i++) {
        int e = base + i * 256 + t;
        if (e < NE) {
            int src = ei[e], dst = ei[NE + e];
            unsigned short rs = (unsigned short)atomicAdd(cntS + i * NN + src, 1);
            unsigned short rd = (unsigned short)atomicAdd(cntD + i * NN + dst, 1);
            rankL[e] = make_ushort2(rs, rd);
        }
    }
}

__device__ __forceinline__ int block_incl_scan(int v, int* s) {
    int t = threadIdx.x;
    s[t] = v; __syncthreads();
#pragma unroll
    for (int off = 1; off < 256; off <<= 1) {
        int u = (t >= off) ? s[t - off] : 0;
        __syncthreads();
        s[t] += u; __syncthreads();
    }
    int r = s[t]; __syncthreads();
    return r;
}

__global__ __launch_bounds__(256) void scan_partial(const int* __restrict__ cntS,
                                                    const int* __restrict__ cntD,
                                                    int* __restrict__ bsumS,
                                                    int* __restrict__ bsumD) {
    __shared__ int s[256];
    int i = blockIdx.x * 256 + threadIdx.x;
    int vs = 0, vd = 0;
    if (i < NN) {
#pragma unroll
        for (int r = 0; r < NREP; r++) {
            vs += cntS[(size_t)r * NN + i];
            vd += cntD[(size_t)r * NN + i];
        }
    }
    int is = block_incl_scan(vs, s);
    int id = block_incl_scan(vd, s);
    if (threadIdx.x == 255) { bsumS[blockIdx.x] = is; bsumD[blockIdx.x] = id; }
}

__global__ __launch_bounds__(256) void scan_blocks(int* __restrict__ bsumS,
                                                   int* __restrict__ bsumD,
                                                   int* __restrict__ bposS,
                                                   int* __restrict__ bposD) {
    __shared__ int s[256];
    int t = threadIdx.x;
    int vs = (t < SCAN_NB) ? bsumS[t] : 0;
    int vd = (t < SCAN_NB) ? bsumD[t] : 0;
    int is = block_incl_scan(vs, s);
    int id = block_incl_scan(vd, s);
    if (t < SCAN_NB) { bposS[t] = is - vs; bposD[t] = id - vd; }
}

// rpS/rpD/invdeg + rewrite cnt[r][n] in place as the global slot base per replica
__global__ __launch_bounds__(256) void scan_final(int* __restrict__ cntS,
                                                  int* __restrict__ cntD,
                                                  const int* __restrict__ bposS,
                                                  const int* __restrict__ bposD,
                                                  int* __restrict__ rpS,
                                                  int* __restrict__ rpD,
                                                  float* __restrict__ invdeg) {
    __shared__ int s[256];
    int i = blockIdx.x * 256 + threadIdx.x;
    int cs[NREP], cd[NREP];
    int vs = 0, vd = 0;
    if (i < NN) {
#pragma unroll
        for (int r = 0; r < NREP; r++) {
            cs[r] = cntS[(size_t)r * NN + i];
            cd[r] = cntD[(size_t)r * NN + i];
            vs += cs[r]; vd += cd[r];
        }
    }
    int is = block_incl_scan(vs, s);
    int id = block_incl_scan(vd, s);
    if (i < NN) {
        int es = bposS[blockIdx.x] + is - vs;
        int ed = bposD[blockIdx.x] + id - vd;
        rpS[i] = es; rpD[i] = ed;
        invdeg[i] = 1.0f / fmaxf((float)vd, 1.0f);
        int run = es;
#pragma unroll
        for (int r = 0; r < NREP; r++) { cntS[(size_t)r * NN + i] = run; run += cs[r]; }
        run = ed;
#pragma unroll
        for (int r = 0; r < NREP; r++) { cntD[(size_t)r * NN + i] = run; run += cd[r]; }
    }
    if (i == NN) { rpS[NN] = NE; rpD[NN] = NE; }
}

// atomic-free permutation scatter: one aligned 16B store per edge
__global__ void scatter_perm(const int* __restrict__ ei, const float* __restrict__ ea,
                             const ushort2* __restrict__ rankL,
                             const int* __restrict__ cntS, const int* __restrict__ cntD,
                             float4* __restrict__ dperm) {
    int e = blockIdx.x * 256 + threadIdx.x;
    if (e >= NE) return;
    int src = ei[e], dst = ei[NE + e];
    int rep = (e >> 8) & (NREP - 1);        // matches rank_edges' iteration slot
    ushort2 rl = rankL[e];
    int sslot = cntS[(size_t)rep * NN + src] + rl.x;
    int dslot = cntD[(size_t)rep * NN + dst] + rl.y;
    float2 a = ((const float2*)ea)[e];
    dperm[sslot] = make_float4(__int_as_float(dslot), 0.0f, a.x, a.y);
}

// ================= per-layer kernels =================

// hx = x @ [g | root] ; h-panel (320 cols) -> bf16 hxh, root (32 cols) -> fp32 hxr
template <int CIN>
__global__ __launch_bounds__(384) void gemm_hx(const float* __restrict__ x,
                                               const float* __restrict__ g,
                                               const float* __restrict__ root,
                                               __hip_bfloat16* __restrict__ hxh,
                                               float* __restrict__ hxr) {
    __shared__ float xs[CIN][36];
    const int n0 = blockIdx.x * 32;
    const int tid = threadIdx.x;
    for (int idx = tid; idx < 32 * CIN; idx += 384) {
        int i = idx / CIN, c = idx % CIN;
        int n = n0 + i;
        xs[c][i] = (n < NN) ? x[(size_t)n * CIN + c] : 0.0f;
    }
    __syncthreads();
    const int j = tid;
    if (j < HCOL + COUT) {
        const bool isg = (j < HCOL);
        const float* w = isg ? (g + j) : (root + (j - HCOL));
        const int ws = isg ? HCOL : COUT;
        float acc[32];
#pragma unroll
        for (int i = 0; i < 32; i++) acc[i] = 0.0f;
        for (int c = 0; c < CIN; c++) {
            float wv = w[(size_t)c * ws];
            const float4* xr = (const float4*)&xs[c][0];
#pragma unroll
            for (int q = 0; q < 8; q++) {
                float4 v = xr[q];
                acc[4 * q + 0] = fmaf(v.x, wv, acc[4 * q + 0]);
                acc[4 * q + 1] = fmaf(v.y, wv, acc[4 * q + 1]);
                acc[4 * q + 2] = fmaf(v.z, wv, acc[4 * q + 2]);
                acc[4 * q + 3] = fmaf(v.w, wv, acc[4 * q + 3]);
            }
        }
        if (isg) {
#pragma unroll
            for (int i = 0; i < 32; i++) {
                int n = n0 + i;
                if (n < NN) hxh[(size_t)n * HCOL + j] = __float2bfloat16(acc[i]);
            }
        } else {
#pragma unroll
            for (int i = 0; i < 32; i++) {
                int n = n0 + i;
                if (n < NN) hxr[(size_t)n * COUT + (j - HCOL)] = acc[i];
            }
        }
    }
}

// Phase A: per-src wave; per 64-edge batch: lane j computes edge j's 10 gaussians
// ONCE into LDS, then halves stream edges with broadcast b128 reads + 10 FMA.
__global__ __launch_bounds__(256) void msg_kernel(const __hip_bfloat16* __restrict__ hxh,
                                                  const int* __restrict__ rpS,
                                                  const float4* __restrict__ dperm,
                                                  const float* __restrict__ mu,
                                                  const float* __restrict__ sigma,
                                                  __hip_bfloat16* __restrict__ m) {
    __shared__ float gws[4][MBATCH][12];     // 12 KB: [wave][edge][10 gw, dpos, pad]
    float muk[2 * KK], isg[2 * KK];
#pragma unroll
    for (int k = 0; k < 2 * KK; k++) {
        muk[k] = mu[k];
        float sv = sigma[k];
        isg[k] = 1.0f / (EPSV + sv * sv);
    }
    const int tid = threadIdx.x;
    const int wave = tid >> 6, lane = tid & 63;
    const int o = lane & 31, h = lane >> 5;
    const int nwaves = gridDim.x * 4;
    for (int n = blockIdx.x * 4 + wave; n < NN; n += nwaves) {
        const int s0 = rpS[n], s1 = rpS[n + 1];
        if (s0 == s1) continue;
        float hreg[KK];
#pragma unroll
        for (int k = 0; k < KK; k++)
            hreg[k] = __bfloat162float(hxh[(size_t)n * HCOL + 32 * k + o]);
        for (int base = s0; base < s1; base += MBATCH) {
            const int cnt = min(MBATCH, s1 - base);
            if (lane < cnt) {                       // phase 1: one edge per lane
                float4 q = dperm[base + lane];
                float wv[12];
#pragma unroll
                for (int k = 0; k < KK; k++) {
                    float d0 = q.z - muk[2 * k];
                    float d1 = q.w - muk[2 * k + 1];
                    wv[k] = __expf(-0.5f * (d0 * d0 * isg[2 * k] + d1 * d1 * isg[2 * k + 1]));
                }
                wv[10] = q.x;                       // dpos bits
                wv[11] = 0.0f;
                float4* row = (float4*)gws[wave][lane];
                row[0] = make_float4(wv[0], wv[1], wv[2], wv[3]);
                row[1] = make_float4(wv[4], wv[5], wv[6], wv[7]);
                row[2] = make_float4(wv[8], wv[9], wv[10], wv[11]);
            }
            __threadfence_block();                  // drain ds_writes (wave-private LDS)
            for (int j = h; j < cnt; j += 2) {      // phase 2: 2 edges per wave-iter
                const float4* row = (const float4*)gws[wave][j];
                float4 g0 = row[0], g1 = row[1], g2 = row[2];
                int dpos = __float_as_int(g2.z);
                float acc = g0.x * hreg[0] + g0.y * hreg[1] + g0.z * hreg[2] + g0.w * hreg[3]
                          + g1.x * hreg[4] + g1.y * hreg[5] + g1.z * hreg[6] + g1.w * hreg[7]
                          + g2.x * hreg[8] + g2.y * hreg[9];
                m[(size_t)dpos * COUT + o] = __float2bfloat16(acc);
            }
            __threadfence_block();                  // reads done before next batch overwrites
        }
    }
}

// Phase B: per-dst wave, packed uint reads (2 bf16/lane), 4 rows/iter; fused epilogue
__global__ __launch_bounds__(256) void gather_kernel(const __hip_bfloat16* __restrict__ m,
                                                     const int* __restrict__ rpD,
                                                     const float* __restrict__ hxr,
                                                     const float* __restrict__ invdeg,
                                                     const float* __restrict__ b,
                                                     float* __restrict__ out) {
    const int tid = threadIdx.x;
    const int wave = tid >> 6, lane = tid & 63;
    const int p = lane & 15;        // uint slot: outputs 2p, 2p+1
    const int h = lane >> 4;        // 0..3
    const int nwaves = gridDim.x * 4;
    const float b0 = b[2 * p], b1 = b[2 * p + 1];
    for (int n = blockIdx.x * 4 + wave; n < NN; n += nwaves) {
        const int s0 = rpD[n], s1 = rpD[n + 1];
        float a0 = 0.0f, a1 = 0.0f;
        for (int s = s0 + h; s < s1; s += 4) {
            unsigned int v = ((const unsigned int*)m)[(size_t)s * 16 + p];
            a0 += __uint_as_float(v << 16);
            a1 += __uint_as_float(v & 0xffff0000u);
        }
        a0 += __shfl_xor(a0, 16); a1 += __shfl_xor(a1, 16);
        a0 += __shfl_xor(a0, 32); a1 += __shfl_xor(a1, 32);
        if (h == 0) {
            float inv = invdeg[n];
            float2 r = ((const float2*)hxr)[(size_t)n * 16 + p];
            float v0 = a0 * inv + r.x + b0;
            float v1 = a1 * inv + r.y + b1;
            v0 = (v0 > 0.0f) ? v0 : (__expf(v0) - 1.0f);
            v1 = (v1 > 0.0f) ? v1 : (__expf(v1) - 1.0f);
            ((float2*)out)[(size_t)n * 16 + p] = make_float2(v0, v1);
        }
    }
}

extern "C" void kernel_launch(void* const* d_in, const int* in_sizes, int n_in,
                              void* d_out, int out_size, void* d_ws, size_t ws_size,
                              hipStream_t stream) {
    const float* graph = (const float*)d_in[0];
    const int* ei = (const int*)d_in[1];
    const float* ea = (const float*)d_in[2];
    const float *G[3], *MU[3], *SG[3], *RT[3], *BB[3];
    for (int l = 0; l < 3; l++) {
        G[l]  = (const float*)d_in[3 + 5 * l + 0];
        MU[l] = (const float*)d_in[3 + 5 * l + 1];
        SG[l] = (const float*)d_in[3 + 5 * l + 2];
        RT[l] = (const float*)d_in[3 + 5 * l + 3];
        BB[l] = (const float*)d_in[3 + 5 * l + 4];
    }
    float* out = (float*)d_out;

    // ---- workspace layout (16B-aligned chunks first) ----
    char* w = (char*)d_ws;
    __hip_bfloat16* hxh = (__hip_bfloat16*)w;   w += (size_t)NN * HCOL * 2;   // 32.0 MB
    float* hxr          = (float*)w;            w += (size_t)NN * COUT * 4;   //  6.4 MB
    __hip_bfloat16* m   = (__hip_bfloat16*)w;   w += (size_t)NE * COUT * 2;   // 51.2 MB
    float4* dperm       = (float4*)w;           w += (size_t)NE * 16;         // 12.8 MB
    ushort2* rankL      = (ushort2*)w;          w += (size_t)NE * 4;          //  3.2 MB
    int* cntS           = (int*)w;              w += (size_t)NREP * NN * 4;   //  0.8 MB
    int* cntD           = (int*)w;              w += (size_t)NREP * NN * 4;   //  0.8 MB (contiguous with cntS)
    float* invdeg       = (float*)w;            w += (size_t)NN * 4;
    int* rpS            = (int*)w;              w += (size_t)(NN + 1) * 4;
    int* rpD            = (int*)w;              w += (size_t)(NN + 1) * 4;
    int* bsumS          = (int*)w;              w += 256 * 4;
    int* bsumD          = (int*)w;              w += 256 * 4;
    int* bposS          = (int*)w;              w += 256 * 4;
    int* bposD          = (int*)w;              w += 256 * 4;

    // ---- CSR build (once): replica-rank -> scan -> atomic-free scatter ----
    hipMemsetAsync(cntS, 0, 2 * NREP * NN * sizeof(int), stream);
    rank_edges<<<(NE + NREP * 256 - 1) / (NREP * 256), 256, 0, stream>>>(ei, cntS, cntD, rankL);
    scan_partial<<<SCAN_NB, 256, 0, stream>>>(cntS, cntD, bsumS, bsumD);
    scan_blocks<<<1, 256, 0, stream>>>(bsumS, bsumD, bposS, bposD);
    scan_final<<<SCAN_NB, 256, 0, stream>>>(cntS, cntD, bposS, bposD, rpS, rpD, invdeg);
    scatter_perm<<<(NE + 255) / 256, 256, 0, stream>>>(ei, ea, rankL, cntS, cntD, dperm);

    for (int l = 0; l < 3; l++) {
        const float* x = (l == 0) ? graph : (out + (size_t)(l - 1) * NN * COUT);
        if (l == 0)
            gemm_hx<64><<<(NN + 31) / 32, 384, 0, stream>>>(x, G[l], RT[l], hxh, hxr);
        else
            gemm_hx<32><<<(NN + 31) / 32, 384, 0, stream>>>(x, G[l], RT[l], hxh, hxr);
        msg_kernel<<<2048, 256, 0, stream>>>(hxh, rpS, dperm, MU[l], SG[l], m);
        gather_kernel<<<2048, 256, 0, stream>>>(m, rpD, hxr, invdeg, BB[l],
                                                out + (size_t)l * NN * COUT);
    }
}